// Round 10
// baseline (379.516 us; speedup 1.0000x reference)
//
#include <hip/hip_runtime.h>
#include <math.h>

// CRF forward partition scan. B=512, S=1024, T=48.
//
// R19: e-prefetch micro-round on the R18 chassis. R18 post-mortem:
// 912 cyc/exec-step (issue 204, stall ~708); issue shaves mostly hide
// in RT shadows. Killed permanently this round (arithmetic):
//  - pairing+compaction: wall = pair-wave union-steps x t_pair = 923k
//    cyc > single 654k (SIMDs are free; concentrating chains loses).
//  - butterfly/swizzle all-gather: 63+ LDS-pipe ops >> 12 broadcast
//    b128 reads (R15 lesson generalizes).
//  - f64-MFMA pass2: K=4 -> 12 serial MFMAs > RT cost + breaks
//    bit-exactness.
// This round: (1) prefetch next exec-step's e via two-level ctz in
// RT2's dead window -> e leaves the lgkm tail at step head, pe is
// instant; (2) block's first e hoisted right after the vmcnt drain.
//  - emission staging via global_load_lds w16, dbl-buffered (R14);
//    TQ/EV in regs (R11+); LDS broadcast both passes (R16); no fences
//    (R17); ctz compaction + first-touch init + max8 (R18).

constexpr int kB  = 512;
constexpr int kS  = 1024;
constexpr int kT  = 48;

typedef float v2 __attribute__((ext_vector_type(2)));
struct V2P { v2 lo, hi; };

#define REP12(X) X(0) X(1) X(2) X(3) X(4) X(5) X(6) X(7) X(8) X(9) X(10) X(11)

// X(k, i0, i1): EV pair k covers transition rows i0=2k, i1=2k+1
#define REP24(X) \
  X(0,0,1)    X(1,2,3)    X(2,4,5)    X(3,6,7) \
  X(4,8,9)    X(5,10,11)  X(6,12,13)  X(7,14,15) \
  X(8,16,17)  X(9,18,19)  X(10,20,21) X(11,22,23) \
  X(12,24,25) X(13,26,27) X(14,28,29) X(15,30,31) \
  X(16,32,33) X(17,34,35) X(18,36,37) X(19,38,39) \
  X(20,40,41) X(21,42,43) X(22,44,45) X(23,46,47)

// X(q, evA, evB, a, b): quad q (rows 4q..4q+3), EV pair ids, acc ids.
// Quads 0,1 are the first touch of all four accs (assign); 2..11 accumulate.
#define REPQ01(X) \
  X(0,0,1,0,3)    X(1,2,3,1,2)
#define REPQR(X) \
  X(2,4,5,2,1)    X(3,6,7,3,0) \
  X(4,8,9,0,3)    X(5,10,11,1,2)  X(6,12,13,2,1)  X(7,14,15,3,0) \
  X(8,16,17,0,3)  X(9,18,19,1,2)  X(10,20,21,2,1) X(11,22,23,3,0)

// Transition column j, rows 4q..4q+3, held in registers for the whole kernel.
#define DECL_TQ(q)  float4 TQ##q;
#define INIT_TQ(q)  { TQ##q.x = trans[(4*(q)+0)*kT + j]; \
                      TQ##q.y = trans[(4*(q)+1)*kT + j]; \
                      TQ##q.z = trans[(4*(q)+2)*kT + j]; \
                      TQ##q.w = trans[(4*(q)+3)*kT + j]; }

#define DECL_EV(k,i0,i1)  v2 EV##k;
#define INIT_EV(k,i0,i1)  EV##k = (v2){__expf(trans[(i0)*kT + j]), \
                                       __expf(trans[(i1)*kT + j])};

// Gathered part vector, prefetched into 12 float4 regs (48 VGPRs).
#define DECL_F(q)  float4 F##q;
#define LOADF(q)   F##q = p4[q];

// Gathered ea vector (12 float4 reads from ea_sh).
#define LOADQ(q)   const float4 Q##q = q4[q];

// pass 1: first-touch assign (bit-identical to max(-inf, t+p)).
#define PASS1I(q,evA,evB,a,b) { \
    const V2P t_ = __builtin_bit_cast(V2P, TQ##q); \
    const V2P p_ = __builtin_bit_cast(V2P, F##q);  \
    mv##a = t_.lo + p_.lo; \
    mv##b = t_.hi + p_.hi; }
// pass 1: accumulate.
#define PASS1(q,evA,evB,a,b) { \
    const V2P t_ = __builtin_bit_cast(V2P, TQ##q); \
    const V2P p_ = __builtin_bit_cast(V2P, F##q);  \
    mv##a = __builtin_elementwise_max(mv##a, t_.lo + p_.lo); \
    mv##b = __builtin_elementwise_max(mv##b, t_.hi + p_.hi); }

// pass 2: first-touch assign via pk_mul (bit-identical to fma(..,0)).
#define PASS2I(q,evA,evB,a,b) { \
    const V2P q_ = __builtin_bit_cast(V2P, Q##q); \
    sv##a = EV##evA * q_.lo; \
    sv##b = EV##evB * q_.hi; }
// pass 2: accumulate (pk_fma).
#define PASS2(q,evA,evB,a,b) { \
    const V2P q_ = __builtin_bit_cast(V2P, Q##q); \
    sv##a = __builtin_elementwise_fma(EV##evA, q_.lo, sv##a); \
    sv##b = __builtin_elementwise_fma(EV##evB, q_.hi, sv##b); }

// 8-way max, depth ~2 via max3-friendly nesting (max is exactly
// reassociative here: no NaNs; +-0 neutral through exp/add downstream).
__device__ __forceinline__ float max8(v2 a, v2 b, v2 c, v2 d) {
    const float t1 = fmaxf(fmaxf(a.x, a.y), b.x);
    const float t2 = fmaxf(fmaxf(b.y, c.x), c.y);
    const float t3 = fmaxf(d.x, d.y);
    return fmaxf(fmaxf(t1, t2), t3);
}

__global__ __launch_bounds__(64, 1) void crf_fwd(
    const float* __restrict__ feats,   // [B, S, T] fp32
    const int*   __restrict__ mask,    // [B, S] int32 (bool)
    const float* __restrict__ trans,   // [T, T] fp32
    float*       __restrict__ out)     // [1 + B]; we write out[1+b]
{
    const int b    = blockIdx.x;
    const int lane = threadIdx.x;
    const int j    = (lane < kT) ? lane : (kT - 1);  // clamp idle lanes

    // Emission staging: 64 rows x 48 floats = 12KB per buffer, dbl-buffered.
    __shared__ alignas(16) float e_sh[2][64 * kT];
    __shared__ alignas(16) float p_sh[64];
    __shared__ alignas(16) float ea_sh[64];
    const float4* p4 = (const float4*)p_sh;
    const float4* q4 = (const float4*)ea_sh;

    const float* fbase = feats + (size_t)b * kS * kT;   // this chain's rows
    const int*   mb    = mask  + (size_t)b * kS;

    // Issue the first 64-row stage EARLY; latency hides under TQ/EV init.
    // 12 calls x (64 lanes x 16B) = 12KB = rows 0..63 (contiguous).
#define STAGE_E(BUFIDX, T0) \
    _Pragma("unroll") \
    for (int c_ = 0; c_ < 12; ++c_) { \
        __builtin_amdgcn_global_load_lds( \
            (const __attribute__((address_space(1))) unsigned int*) \
                (fbase + (size_t)(T0) * kT + c_ * 256 + lane * 4), \
            (__attribute__((address_space(3))) unsigned int*) \
                (&e_sh[BUFIDX][c_ * 256]), \
            16, 0, 0); \
    }

    STAGE_E(0, 0)

    // T column and E column in registers.
    REP12(DECL_TQ)
    REP12(INIT_TQ)
    REP24(DECL_EV)
    REP24(INIT_EV)
    REP12(DECL_F)

    // part0 = emit[0] + transition[T-2, :]   (row 46, column j)
    float part = fbase[j] + trans[(kT - 2) * kT + j];
    p_sh[lane] = part;
    REP12(LOADF)      // ordered after the store by same-array aliasing;
                      // valid until next p_sh write

    int mreg = mb[lane];   // mask words for steps 0..63 (coalesced)
    int buf  = 0;

    for (int blk = 0; blk < 16; ++blk) {
        // Drain staging: e_sh[buf] + mreg were issued ~64 steps ago (or at
        // init) -> this wait is effectively free.
        asm volatile("s_waitcnt vmcnt(0)" ::: "memory");

        // Uniform 64-step mask bitmask in an SGPR pair; compacted
        // iteration via ctz -- masked steps cost nothing at all.
        unsigned long long bits = __ballot(mreg != 0);
        if (blk == 0) bits &= ~1ull;            // scan starts at step 1
        if (blk < 15) {
            mreg = mb[(blk + 1) * 64 + lane];   // next block's mask word
            STAGE_E(buf ^ 1, (blk + 1) * 64)    // next block's emission rows
        }

        // Prefetch the block's first emission value (uniform branch).
        float e_cur = 0.f;
        if (bits) e_cur = e_sh[buf][(int)__builtin_ctzll(bits) * kT + j];

        while (bits) {
            bits &= bits - 1;
            const float e = e_cur;
            const float pe = part - e;  // off the M-critical path

            // pass 1 on prefetched F: M_j = max_i (T[i,j] + part_i)
            v2 mv0, mv1, mv2, mv3;
            REPQ01(PASS1I)
            REPQR(PASS1)
            const float M = max8(mv0, mv1, mv2, mv3);
            const float c2 = 2.0f * e + M;   // hoisted ahead of the ea RT

            // lane i publishes ea_i = exp(part_i - e_i - M_i).
            // Ordering vs prior LOADQ reads of ea_sh: same-array WAR,
            // respected by the compiler; HW LDS pipe is in-order.
            const float ea = __expf(pe - M);
            ea_sh[lane] = ea;

            // Prefetch NEXT exec-step's e in RT2's dead window; removes
            // the e read from the next step's lgkm tail entirely.
            if (bits)
                e_cur = e_sh[buf][(int)__builtin_ctzll(bits) * kT + j];

            // pass 2: S_j = sum_i exp(T[i,j]) * ea_i   (pk chain)
            REP12(LOADQ)
            v2 sv0, sv1, sv2, sv3;
            REPQ01(PASS2I)
            REPQR(PASS2)
            sv0 = sv0 + sv1;
            sv2 = sv2 + sv3;
            sv0 = sv0 + sv2;
            const float Ssum = sv0.x + sv0.y;

            part = c2 + __logf(Ssum);

            // publish part (ordered after LOADF reads by same-array WAR)
            // and refresh the gather; F stays valid across masked steps.
            p_sh[lane] = part;
            REP12(LOADF)
        }
        buf ^= 1;
    }

    // Final transition-only step; only end_value[:, T-1] is stored.
    // F regs hold the current gathered part (prefetch invariant).
    {
        v2 mv0, mv1, mv2, mv3;
        REPQ01(PASS1I)
        REPQR(PASS1)
        const float M = max8(mv0, mv1, mv2, mv3);
        const float ea = __expf(part - M);   // no emission in final step
        ea_sh[lane] = ea;

        REP12(LOADQ)
        v2 sv0, sv1, sv2, sv3;
        REPQ01(PASS2I)
        REPQR(PASS2)
        sv0 = sv0 + sv1;
        sv2 = sv2 + sv3;
        sv0 = sv0 + sv2;
        const float Ssum = sv0.x + sv0.y;
        const float val = M + __logf(Ssum);
        if (lane == kT - 1) out[1 + b] = val;  // score[b] = end_value[b,-1]
    }
}

// out[0] = sum(score). Single wave; no barriers needed.
__global__ __launch_bounds__(64) void sum_scores(
    const float* __restrict__ sc, float* __restrict__ out)
{
    float s = 0.f;
    for (int i = (int)threadIdx.x; i < kB; i += 64) s += sc[i];
#pragma unroll
    for (int off = 32; off > 0; off >>= 1) s += __shfl_down(s, off);
    if (threadIdx.x == 0) out[0] = s;
}

extern "C" void kernel_launch(void* const* d_in, const int* in_sizes, int n_in,
                              void* d_out, int out_size, void* d_ws, size_t ws_size,
                              hipStream_t stream) {
    const float* feats = (const float*)d_in[0];
    const int*   mask  = (const int*)d_in[1];
    const float* trans = (const float*)d_in[2];
    float*       out   = (float*)d_out;

    crf_fwd<<<dim3(kB), dim3(64), 0, stream>>>(feats, mask, trans, out);
    sum_scores<<<dim3(1), dim3(64), 0, stream>>>(out + 1, out);
}

// Round 11
// 376.034 us; speedup vs baseline: 1.0093x; 1.0093x over previous
//
#include <hip/hip_runtime.h>
#include <math.h>

// CRF forward partition scan. B=512, S=1024, T=48.
//
// R20: revert to R18 (measured best, 272.5 +-0.6us). R19's e-prefetch
// package REGRESSED to 278.9 +-0.5 (extra uniform branch + dup ctz on
// the critical loop; the e-read it replaced was already latency-hidden).
// Cycle model now CLOSES: broadcast ds_read_b128 returns 1KB -> ~12cyc
// pipe each (m134); per step 24 reads ~288cyc IN SERIES with 2 exposed
// write->read turnarounds (~150 ea) + ~200 VALU issue + sibling-wave
// LDS contention (2 waves/CU, ~170) ~= 910 ~= measured 912. Readlane
// alternative moves 64x less data but measured worse (R12/R13/R16:
// VALU->SGPR hazard serialization); fixing it needs full-asm register
// pinning -- negative EV headless. Algorithmic restructurings all killed
// by arithmetic (R15-R19): the repo's quirky LSE (subtracts m_i) forces
// exchange(part) -> pass1 -> exchange(f(M)) -> pass2 per step.
// Structure (all measured-in): emission staged via global_load_lds w16
// dbl-buffered (R14); TQ/EV in regs (R11+); LDS broadcast both passes
// with pk ops (R16); no fences (R17); ctz compaction + first-touch init
// + max8 (R18).

constexpr int kB  = 512;
constexpr int kS  = 1024;
constexpr int kT  = 48;

typedef float v2 __attribute__((ext_vector_type(2)));
struct V2P { v2 lo, hi; };

#define REP12(X) X(0) X(1) X(2) X(3) X(4) X(5) X(6) X(7) X(8) X(9) X(10) X(11)

// X(k, i0, i1): EV pair k covers transition rows i0=2k, i1=2k+1
#define REP24(X) \
  X(0,0,1)    X(1,2,3)    X(2,4,5)    X(3,6,7) \
  X(4,8,9)    X(5,10,11)  X(6,12,13)  X(7,14,15) \
  X(8,16,17)  X(9,18,19)  X(10,20,21) X(11,22,23) \
  X(12,24,25) X(13,26,27) X(14,28,29) X(15,30,31) \
  X(16,32,33) X(17,34,35) X(18,36,37) X(19,38,39) \
  X(20,40,41) X(21,42,43) X(22,44,45) X(23,46,47)

// X(q, evA, evB, a, b): quad q (rows 4q..4q+3), EV pair ids, acc ids.
// Quads 0,1 are the first touch of all four accs (assign); 2..11 accumulate.
#define REPQ01(X) \
  X(0,0,1,0,3)    X(1,2,3,1,2)
#define REPQR(X) \
  X(2,4,5,2,1)    X(3,6,7,3,0) \
  X(4,8,9,0,3)    X(5,10,11,1,2)  X(6,12,13,2,1)  X(7,14,15,3,0) \
  X(8,16,17,0,3)  X(9,18,19,1,2)  X(10,20,21,2,1) X(11,22,23,3,0)

// Transition column j, rows 4q..4q+3, held in registers for the whole kernel.
#define DECL_TQ(q)  float4 TQ##q;
#define INIT_TQ(q)  { TQ##q.x = trans[(4*(q)+0)*kT + j]; \
                      TQ##q.y = trans[(4*(q)+1)*kT + j]; \
                      TQ##q.z = trans[(4*(q)+2)*kT + j]; \
                      TQ##q.w = trans[(4*(q)+3)*kT + j]; }

#define DECL_EV(k,i0,i1)  v2 EV##k;
#define INIT_EV(k,i0,i1)  EV##k = (v2){__expf(trans[(i0)*kT + j]), \
                                       __expf(trans[(i1)*kT + j])};

// Gathered part vector, prefetched into 12 float4 regs (48 VGPRs).
#define DECL_F(q)  float4 F##q;
#define LOADF(q)   F##q = p4[q];

// Gathered ea vector (12 float4 reads from ea_sh).
#define LOADQ(q)   const float4 Q##q = q4[q];

// pass 1: first-touch assign (bit-identical to max(-inf, t+p)).
#define PASS1I(q,evA,evB,a,b) { \
    const V2P t_ = __builtin_bit_cast(V2P, TQ##q); \
    const V2P p_ = __builtin_bit_cast(V2P, F##q);  \
    mv##a = t_.lo + p_.lo; \
    mv##b = t_.hi + p_.hi; }
// pass 1: accumulate.
#define PASS1(q,evA,evB,a,b) { \
    const V2P t_ = __builtin_bit_cast(V2P, TQ##q); \
    const V2P p_ = __builtin_bit_cast(V2P, F##q);  \
    mv##a = __builtin_elementwise_max(mv##a, t_.lo + p_.lo); \
    mv##b = __builtin_elementwise_max(mv##b, t_.hi + p_.hi); }

// pass 2: first-touch assign via pk_mul (bit-identical to fma(..,0)).
#define PASS2I(q,evA,evB,a,b) { \
    const V2P q_ = __builtin_bit_cast(V2P, Q##q); \
    sv##a = EV##evA * q_.lo; \
    sv##b = EV##evB * q_.hi; }
// pass 2: accumulate (pk_fma).
#define PASS2(q,evA,evB,a,b) { \
    const V2P q_ = __builtin_bit_cast(V2P, Q##q); \
    sv##a = __builtin_elementwise_fma(EV##evA, q_.lo, sv##a); \
    sv##b = __builtin_elementwise_fma(EV##evB, q_.hi, sv##b); }

// 8-way max, depth 2 (max is exactly reassociative here: no NaNs, and
// any +-0 ambiguity is value-neutral through exp/add downstream).
__device__ __forceinline__ float max8(v2 a, v2 b, v2 c, v2 d) {
    const float t1 = fmaxf(fmaxf(a.x, a.y), b.x);
    const float t2 = fmaxf(fmaxf(b.y, c.x), c.y);
    const float t3 = fmaxf(d.x, d.y);
    return fmaxf(fmaxf(t1, t2), t3);
}

__global__ __launch_bounds__(64, 1) void crf_fwd(
    const float* __restrict__ feats,   // [B, S, T] fp32
    const int*   __restrict__ mask,    // [B, S] int32 (bool)
    const float* __restrict__ trans,   // [T, T] fp32
    float*       __restrict__ out)     // [1 + B]; we write out[1+b]
{
    const int b    = blockIdx.x;
    const int lane = threadIdx.x;
    const int j    = (lane < kT) ? lane : (kT - 1);  // clamp idle lanes

    // Emission staging: 64 rows x 48 floats = 12KB per buffer, dbl-buffered.
    __shared__ alignas(16) float e_sh[2][64 * kT];
    __shared__ alignas(16) float p_sh[64];
    __shared__ alignas(16) float ea_sh[64];
    const float4* p4 = (const float4*)p_sh;
    const float4* q4 = (const float4*)ea_sh;

    const float* fbase = feats + (size_t)b * kS * kT;   // this chain's rows
    const int*   mb    = mask  + (size_t)b * kS;

    // Issue the first 64-row stage EARLY; latency hides under TQ/EV init.
    // 12 calls x (64 lanes x 16B) = 12KB = rows 0..63 (contiguous).
#define STAGE_E(BUFIDX, T0) \
    _Pragma("unroll") \
    for (int c_ = 0; c_ < 12; ++c_) { \
        __builtin_amdgcn_global_load_lds( \
            (const __attribute__((address_space(1))) unsigned int*) \
                (fbase + (size_t)(T0) * kT + c_ * 256 + lane * 4), \
            (__attribute__((address_space(3))) unsigned int*) \
                (&e_sh[BUFIDX][c_ * 256]), \
            16, 0, 0); \
    }

    STAGE_E(0, 0)

    // T column and E column in registers.
    REP12(DECL_TQ)
    REP12(INIT_TQ)
    REP24(DECL_EV)
    REP24(INIT_EV)
    REP12(DECL_F)

    // part0 = emit[0] + transition[T-2, :]   (row 46, column j)
    float part = fbase[j] + trans[(kT - 2) * kT + j];
    p_sh[lane] = part;
    REP12(LOADF)      // ordered after the store by same-array aliasing;
                      // valid until next p_sh write

    int mreg = mb[lane];   // mask words for steps 0..63 (coalesced)
    int buf  = 0;

    for (int blk = 0; blk < 16; ++blk) {
        // Drain staging: e_sh[buf] + mreg were issued ~64 steps ago (or at
        // init) -> this wait is effectively free.
        asm volatile("s_waitcnt vmcnt(0)" ::: "memory");

        // Uniform 64-step mask bitmask in an SGPR pair; compacted
        // iteration via ctz -- masked steps cost nothing at all.
        unsigned long long bits = __ballot(mreg != 0);
        if (blk == 0) bits &= ~1ull;            // scan starts at step 1
        if (blk < 15) {
            mreg = mb[(blk + 1) * 64 + lane];   // next block's mask word
            STAGE_E(buf ^ 1, (blk + 1) * 64)    // next block's emission rows
        }

        while (bits) {
            const int idx = (int)__builtin_ctzll(bits);  // SALU s_ff1
            bits &= bits - 1;

            // e from LDS; latency hides under pass1 (first use is ea).
            const float e = e_sh[buf][idx * kT + j];
            const float pe = part - e;  // off the M-critical path

            // pass 1 on prefetched F: M_j = max_i (T[i,j] + part_i)
            v2 mv0, mv1, mv2, mv3;
            REPQ01(PASS1I)
            REPQR(PASS1)
            const float M = max8(mv0, mv1, mv2, mv3);
            const float c2 = 2.0f * e + M;   // hoisted ahead of the ea RT

            // lane i publishes ea_i = exp(part_i - e_i - M_i).
            // Ordering vs prior LOADQ reads of ea_sh: same-array WAR,
            // respected by the compiler; HW LDS pipe is in-order.
            const float ea = __expf(pe - M);
            ea_sh[lane] = ea;

            // pass 2: S_j = sum_i exp(T[i,j]) * ea_i   (pk chain)
            REP12(LOADQ)
            v2 sv0, sv1, sv2, sv3;
            REPQ01(PASS2I)
            REPQR(PASS2)
            sv0 = sv0 + sv1;
            sv2 = sv2 + sv3;
            sv0 = sv0 + sv2;
            const float Ssum = sv0.x + sv0.y;

            part = c2 + __logf(Ssum);

            // publish part (ordered after LOADF reads by same-array WAR)
            // and refresh the gather; F stays valid across masked steps.
            p_sh[lane] = part;
            REP12(LOADF)
        }
        buf ^= 1;
    }

    // Final transition-only step; only end_value[:, T-1] is stored.
    // F regs hold the current gathered part (prefetch invariant).
    {
        v2 mv0, mv1, mv2, mv3;
        REPQ01(PASS1I)
        REPQR(PASS1)
        const float M = max8(mv0, mv1, mv2, mv3);
        const float ea = __expf(part - M);   // no emission in final step
        ea_sh[lane] = ea;

        REP12(LOADQ)
        v2 sv0, sv1, sv2, sv3;
        REPQ01(PASS2I)
        REPQR(PASS2)
        sv0 = sv0 + sv1;
        sv2 = sv2 + sv3;
        sv0 = sv0 + sv2;
        const float Ssum = sv0.x + sv0.y;
        const float val = M + __logf(Ssum);
        if (lane == kT - 1) out[1 + b] = val;  // score[b] = end_value[b,-1]
    }
}

// out[0] = sum(score). Single wave; no barriers needed.
__global__ __launch_bounds__(64) void sum_scores(
    const float* __restrict__ sc, float* __restrict__ out)
{
    float s = 0.f;
    for (int i = (int)threadIdx.x; i < kB; i += 64) s += sc[i];
#pragma unroll
    for (int off = 32; off > 0; off >>= 1) s += __shfl_down(s, off);
    if (threadIdx.x == 0) out[0] = s;
}

extern "C" void kernel_launch(void* const* d_in, const int* in_sizes, int n_in,
                              void* d_out, int out_size, void* d_ws, size_t ws_size,
                              hipStream_t stream) {
    const float* feats = (const float*)d_in[0];
    const int*   mask  = (const int*)d_in[1];
    const float* trans = (const float*)d_in[2];
    float*       out   = (float*)d_out;

    crf_fwd<<<dim3(kB), dim3(64), 0, stream>>>(feats, mask, trans, out);
    sum_scores<<<dim3(1), dim3(64), 0, stream>>>(out + 1, out);
}